// Round 12
// baseline (282.886 us; speedup 1.0000x reference)
//
#include <hip/hip_runtime.h>
#include <hip/hip_bf16.h>

#define WINDOW 5
#define DIM 1024
#define FEAT 1024
#define SEQ 128
#define BATCH 128
#define MTOT (BATCH*SEQ)      // 16384
#define NTOT (WINDOW*FEAT)    // 5120
#define KTOT 1024

#define DCHUNK 16             // d-rows per partial-absmax block

typedef int int4v __attribute__((ext_vector_type(4)));

static __device__ __forceinline__ unsigned short f2bf(float f) {
  union { float f; unsigned int i; } c; c.f = f;
  unsigned int i = c.i;
  unsigned int lsb = (i >> 16) & 1u;
  i += 0x7fffu + lsb;            // round-to-nearest-even
  return (unsigned short)(i >> 16);
}
static __device__ __forceinline__ float bf2f(unsigned short u) {
  union { unsigned int i; float f; } c; c.i = ((unsigned int)u) << 16; return c.f;
}
static __device__ __forceinline__ signed char q8(float v, float inv) {
  float q = rintf(v * inv);
  q = fminf(fmaxf(q, -127.f), 127.f);
  return (signed char)(int)q;
}

// ---------------- x fp32 -> i8, per-row scale, FRAGMENT-ORDERED output ----------------
// xqf layout: [mtile=m>>4][kstep=k>>6][lane][16B], lane=(m&15)+16*((k>>4)&3), byte=k&15.
// A wave's MFMA fragment load is then base+lane*16 = one contiguous 1KB burst.
__global__ __launch_bounds__(256) void quant_x(const float* __restrict__ x,
                                               signed char* __restrict__ xqf,
                                               float* __restrict__ sx) {
  int row  = blockIdx.x * 4 + (threadIdx.x >> 6);   // one wave per row
  int lane = threadIdx.x & 63;
  const float* xr = x + (size_t)row * KTOT;

  float4 v[4];
  float amax = 0.f;
  #pragma unroll
  for (int i = 0; i < 4; i++) {
    v[i] = ((const float4*)xr)[i * 64 + lane];
    amax = fmaxf(amax, fmaxf(fmaxf(fabsf(v[i].x), fabsf(v[i].y)),
                             fmaxf(fabsf(v[i].z), fabsf(v[i].w))));
  }
  #pragma unroll
  for (int m = 1; m < 64; m <<= 1)
    amax = fmaxf(amax, __shfl_xor(amax, m));

  float inv = amax > 0.f ? 127.f / amax : 0.f;
  const int mtile = row >> 4, mr = row & 15;
  #pragma unroll
  for (int i = 0; i < 4; i++) {
    int p = ((int)(unsigned char)q8(v[i].x, inv)) |
            ((int)(unsigned char)q8(v[i].y, inv) << 8) |
            ((int)(unsigned char)q8(v[i].z, inv) << 16) |
            ((int)q8(v[i].w, inv) << 24);
    int k = i * 256 + lane * 4;
    size_t addr = ((size_t)(mtile * 16 + (k >> 6))) * 1024
                + (size_t)((mr + 16 * ((k >> 4) & 3)) * 16 + (k & 15));
    *(int*)(xqf + addr) = p;
  }
  if (lane == 0) sx[row] = amax / 127.f;
}

// ---------------- per-(w,f) column absmax, stage 1: coalesced partials ----------------
__global__ __launch_bounds__(256) void w_colamax_part(const float* __restrict__ Ws,
                                                      float* __restrict__ part) {
  int w  = blockIdx.z;
  int dc = blockIdx.y;
  int f4 = threadIdx.x;
  const float* p = Ws + ((size_t)w * DIM + (size_t)dc * DCHUNK) * FEAT;
  float4 m = {0.f, 0.f, 0.f, 0.f};
  #pragma unroll
  for (int d = 0; d < DCHUNK; d++) {
    float4 v = ((const float4*)(p + (size_t)d * FEAT))[f4];
    m.x = fmaxf(m.x, fabsf(v.x));
    m.y = fmaxf(m.y, fabsf(v.y));
    m.z = fmaxf(m.z, fabsf(v.z));
    m.w = fmaxf(m.w, fabsf(v.w));
  }
  ((float4*)(part + ((size_t)w * (DIM / DCHUNK) + dc) * FEAT))[f4] = m;
}

// ---------------- stage 2: fold partials -> sw = amax/127 ----------------
__global__ __launch_bounds__(256) void w_colamax_reduce(const float* __restrict__ part,
                                                        float* __restrict__ sw) {
  int idx = blockIdx.x * 256 + threadIdx.x;   // w*1024 + f, 5120 total
  int w = idx >> 10, f = idx & 1023;
  const float* p = part + (size_t)w * (DIM / DCHUNK) * FEAT + f;
  float m = 0.f;
  #pragma unroll 8
  for (int c = 0; c < DIM / DCHUNK; c++)
    m = fmaxf(m, p[(size_t)c * FEAT]);
  sw[idx] = m / 127.f;
}

// ---------------- Ws -> FRAGMENT-ORDERED i8 wqf ----------------
// wqf layout: [tile = w*64 + f>>4][kstep = d>>6][lane][16B], lane=(f&15)+16*((d>>4)&3).
// Block: 64 d x 64 f of one w. Read coalesced into LDS, write 16B slots per thread.
__global__ __launch_bounds__(256) void transq_ws(const float* __restrict__ Ws,
                                                 const float* __restrict__ sw,
                                                 signed char* __restrict__ wqf) {
  __shared__ float tile[64][65];
  int w  = blockIdx.z;
  int f0 = blockIdx.x * 64, d0 = blockIdx.y * 64;
  int t  = threadIdx.x;
  {
    int drow = t >> 4, ff4 = (t & 15) * 4;
    const float* src = Ws + ((size_t)w * DIM + d0) * FEAT + f0;
    #pragma unroll
    for (int p = 0; p < 4; p++) {
      int d = p * 16 + drow;
      float4 v = *(const float4*)(src + (size_t)d * FEAT + ff4);
      tile[d][ff4]     = v.x;
      tile[d][ff4 + 1] = v.y;
      tile[d][ff4 + 2] = v.z;
      tile[d][ff4 + 3] = v.w;
    }
  }
  __syncthreads();
  {
    int fl = t & 63, ks = t >> 6;
    float swv = sw[(w << 10) + f0 + fl];
    float inv = swv > 0.f ? 1.0f / swv : 0.f;
    unsigned int pk[4];
    #pragma unroll
    for (int g = 0; g < 4; g++) {
      unsigned int acc = 0;
      #pragma unroll
      for (int e = 0; e < 4; e++)
        acc |= ((unsigned int)(unsigned char)q8(tile[ks * 16 + g * 4 + e][fl], inv)) << (8 * e);
      pk[g] = acc;
    }
    size_t addr = ((size_t)((w * 64 + ((f0 + fl) >> 4)) * 16 + (d0 >> 6))) * 1024
                + (size_t)(((fl & 15) + 16 * ks) * 16);
    *(int4v*)(wqf + addr) = (int4v){(int)pk[0], (int)pk[1], (int)pk[2], (int)pk[3]};
  }
}

// ---------------- fused barrier-free GEMM(i8) + dequant + max-plus scan + tanh ----------------
// 256 thr (4 waves, 2M x 2N), tile = 128 l x 160 c (5w x 32f). NO LDS staging, NO
// barriers in the K-loop: operands are pre-permuted to fragment order, so each
// fragment load is ONE coalesced 1KB global_load_dwordx4 burst (fixes r9's 16-line
// scatter). 16 unrolled K-steps, explicit even/odd register double-buffer. LDS holds
// only the proj scan tile (r7's verified conflict-free layout).
__global__ __launch_bounds__(256, 2) void fused_gemm_scan(
    const signed char* __restrict__ xqf,  // fragment-ordered A
    const signed char* __restrict__ wqf,  // fragment-ordered B
    const float* __restrict__ sx,         // [MTOT]
    const float* __restrict__ swp,        // [W*FEAT]
    const float* __restrict__ bias,       // [FEAT]
    float* __restrict__ out)              // [BATCH][FEAT]
{
  __shared__ __align__(16) char smem[40960];

  const int tid  = threadIdx.x;
  const int wid  = tid >> 6;
  const int lane = tid & 63;

  // XCD-chunked swizzle (4096 % 8 == 0 -> bijective); work = b*32 + fslice
  int bid = blockIdx.x;
  int wg  = ((bid & 7) << 9) + (bid >> 3);
  const int b  = wg >> 5;
  const int f0 = (wg & 31) << 5;

  const int wm = wid >> 1, wn = wid & 1;     // wave tile: 64 M x 80 N

  // fragment base pointers (each +lane*16 -> contiguous 1KB per wave)
  const signed char* aB[4];
  #pragma unroll
  for (int i = 0; i < 4; i++) {
    int mt = b * 8 + wm * 4 + i;
    aB[i] = xqf + (size_t)mt * 16384 + lane * 16;
  }
  const signed char* bB[5];
  #pragma unroll
  for (int j = 0; j < 5; j++) {
    int c  = wn * 80 + j * 16;
    int tl = (c >> 5) * 64 + (f0 >> 4) + ((c >> 4) & 1);
    bB[j] = wqf + (size_t)tl * 16384 + lane * 16;
  }

  int4v acc[4][5];
  #pragma unroll
  for (int i = 0; i < 4; i++)
    #pragma unroll
    for (int j = 0; j < 5; j++)
      acc[i][j] = (int4v){0, 0, 0, 0};

  // 16 K-steps, even/odd explicit double-buffer (static names; rule #20)
  int4v aE[4], bE[5], aO[4], bO[5];
  #pragma unroll
  for (int i = 0; i < 4; i++) aE[i] = *(const int4v*)(aB[i]);
  #pragma unroll
  for (int j = 0; j < 5; j++) bE[j] = *(const int4v*)(bB[j]);

  #pragma unroll
  for (int sb = 0; sb < 8; sb++) {
    const int se = sb * 2;          // even step computed from aE/bE
    // prefetch odd step se+1
    #pragma unroll
    for (int i = 0; i < 4; i++) aO[i] = *(const int4v*)(aB[i] + (se & 3) * 1024 + 1024);
    #pragma unroll
    for (int j = 0; j < 5; j++) bO[j] = *(const int4v*)(bB[j] + (se & 3) * 1024 + 1024);
    #pragma unroll
    for (int i = 0; i < 4; i++)
      #pragma unroll
      for (int j = 0; j < 5; j++)
        acc[i][j] = __builtin_amdgcn_mfma_i32_16x16x64_i8(aE[i], bE[j], acc[i][j], 0, 0, 0);
    // advance pointers every 4 steps (keep 13-bit imm offsets small)
    if ((se & 3) == 2) {
      #pragma unroll
      for (int i = 0; i < 4; i++) aB[i] += 4096;
      #pragma unroll
      for (int j = 0; j < 5; j++) bB[j] += 4096;
    }
    // prefetch even step se+2
    if (sb < 7) {
      const int nse = se + 2;
      #pragma unroll
      for (int i = 0; i < 4; i++) aE[i] = *(const int4v*)(aB[i] + (nse & 3) * 1024);
      #pragma unroll
      for (int j = 0; j < 5; j++) bE[j] = *(const int4v*)(bB[j] + (nse & 3) * 1024);
    }
    #pragma unroll
    for (int i = 0; i < 4; i++)
      #pragma unroll
      for (int j = 0; j < 5; j++)
        acc[i][j] = __builtin_amdgcn_mfma_i32_16x16x64_i8(aO[i], bO[j], acc[i][j], 0, 0, 0);
  }

  // ---- dequant -> bf16 proj tile in LDS [128][320B], byte ^ ((l>>2)&3)<<5 ----
  float sxv[16];
  #pragma unroll
  for (int i = 0; i < 4; i++)
    #pragma unroll
    for (int r = 0; r < 4; r++)
      sxv[i * 4 + r] = sx[b * SEQ + wm * 64 + i * 16 + ((lane >> 4) << 2) + r];
  float swv[5];
  #pragma unroll
  for (int j = 0; j < 5; j++) {
    int c = wn * 80 + j * 16 + (lane & 15);
    swv[j] = swp[((c >> 5) << 10) + f0 + (c & 31)];
  }

  #pragma unroll
  for (int i = 0; i < 4; i++) {
    #pragma unroll
    for (int j = 0; j < 5; j++) {
      #pragma unroll
      for (int r = 0; r < 4; r++) {
        int l = wm * 64 + i * 16 + ((lane >> 4) << 2) + r;
        int c = wn * 80 + j * 16 + (lane & 15);
        float v = (float)acc[i][j][r] * sxv[i * 4 + r] * swv[j];
        int byte = ((l * 160 + c) << 1) ^ (((l >> 2) & 3) << 5);
        *(unsigned short*)(smem + byte) = f2bf(v);
      }
    }
  }
  __syncthreads();

  // ---- max-plus scan over l, one thread per f-column (conflict-free reads) ----
  if (tid < 32) {
    const int f = tid;
    float h0 = 0.f, h1 = 0.f, h2 = 0.f, h3 = 0.f, h4 = 0.f;
    for (int l = 0; l < SEQ; l++) {
      const int swz  = ((l >> 2) & 3) << 5;
      const int base = l * 320;
      float p[5];
      #pragma unroll
      for (int w = 0; w < 5; w++) {
        int byte = (base + (((w << 5) + f) << 1)) ^ swz;
        p[w] = bf2f(*(const unsigned short*)(smem + byte));
      }
      h4 = fmaxf(h3 + p[4], h4);
      h3 = fmaxf(h2 + p[3], h3);
      h2 = fmaxf(h1 + p[2], h2);
      h1 = fmaxf(h0 + p[1], h1);
      h0 = fmaxf(p[0], h0);
    }
    out[b * FEAT + f0 + f] = tanhf(h4 + bias[f0 + f]);
  }
}

extern "C" void kernel_launch(void* const* d_in, const int* in_sizes, int n_in,
                              void* d_out, int out_size, void* d_ws, size_t ws_size,
                              hipStream_t stream) {
  const float* x  = (const float*)d_in[0];
  const float* Ws = (const float*)d_in[1];
  const float* b  = (const float*)d_in[2];
  float* out = (float*)d_out;

  char* ws = (char*)d_ws;
  const size_t XQ_BYTES = (size_t)MTOT * KTOT;                  // 16,777,216
  const size_t WQ_BYTES = (size_t)WINDOW * FEAT * DIM;          //  5,242,880
  const size_t SX_BYTES = (size_t)MTOT * 4;                     //     65,536
  const size_t SW_BYTES = (size_t)WINDOW * FEAT * 4;            //     20,480
  signed char* xqf = (signed char*)ws;
  signed char* wqf = (signed char*)(ws + XQ_BYTES);
  float* sx   = (float*)(ws + XQ_BYTES + WQ_BYTES);
  float* sw   = (float*)(ws + XQ_BYTES + WQ_BYTES + SX_BYTES);
  float* part = (float*)(ws + XQ_BYTES + WQ_BYTES + SX_BYTES + SW_BYTES);

  hipLaunchKernelGGL(quant_x, dim3(MTOT / 4), dim3(256), 0, stream, x, xqf, sx);
  hipLaunchKernelGGL(w_colamax_part, dim3(1, DIM / DCHUNK, WINDOW), dim3(256), 0, stream,
                     Ws, part);
  hipLaunchKernelGGL(w_colamax_reduce, dim3(NTOT / 256), dim3(256), 0, stream, part, sw);
  hipLaunchKernelGGL(transq_ws, dim3(FEAT / 64, DIM / 64, WINDOW), dim3(256), 0, stream,
                     Ws, sw, wqf);
  hipLaunchKernelGGL(fused_gemm_scan, dim3(BATCH * 32), dim3(256), 0, stream,
                     xqf, wqf, sx, sw, b, out);
}